// Round 7
// baseline (209.404 us; speedup 1.0000x reference)
//
#include <hip/hip_runtime.h>

#define NB 16
#define NTQ 256
#define NTK 256
#define ND 256
#define NF 36
#define NH 8
#define NDK 32
#define NSF 6

typedef __attribute__((ext_vector_type(8))) short short8;
typedef __attribute__((ext_vector_type(4))) float f32x4;
#define MFMA16(a,b,c) __builtin_amdgcn_mfma_f32_16x16x32_bf16(a,b,c,0,0,0)

// ---- workspace byte offsets ----
// RT: [b][80][256] bf16 (f'=2f: m*v, f'=2f+1: m)
#define RT_OFF   524288u
// projected Q/K hi/lo: [b][j][t][dk] bf16, 4MB each
#define QPH_OFF  (2u*1024*1024)
#define QPL_OFF  (6u*1024*1024)
#define KPH_OFF  (10u*1024*1024)
#define KPL_OFF  (14u*1024*1024)

__device__ __forceinline__ short f2bf(float x){
    union { float f; unsigned u; } v; v.f = x;
    unsigned r = v.u + 0x7fffu + ((v.u >> 16) & 1u);
    return (short)(r >> 16);
}
__device__ __forceinline__ float bf2f(short s){
    union { float f; unsigned u; } v; v.u = ((unsigned)(unsigned short)s) << 16;
    return v.f;
}
__device__ __forceinline__ float fast_tanh(float x){
    float e = __expf(2.0f*x);
    return 1.0f - 2.0f/(e + 1.0f);
}
__device__ __forceinline__ short8 ld8(const short* p){ return *(const short8*)p; }

// hi/lo bf16 split of 8 consecutive floats (RNE hi, RNE residual lo)
__device__ __forceinline__ void cvt8(const float* __restrict__ p, short8& h8, short8& l8){
    f32x4 a = *(const f32x4*)p;
    f32x4 c = *(const f32x4*)(p + 4);
    #pragma unroll
    for (int i = 0; i < 4; ++i){
        short h0 = f2bf(a[i]); h8[i]   = h0; l8[i]   = f2bf(a[i] - bf2f(h0));
        short h1 = f2bf(c[i]); h8[4+i] = h1; l8[4+i] = f2bf(c[i] - bf2f(h1));
    }
}

// ---------------- kernel 1: projection GEMM (W staged in LDS) + RT pack (R6 verbatim) ----------------
__global__ __launch_bounds__(256, 4)
void imta_proj(const float* __restrict__ query, const float* __restrict__ key_ts,
               const float* __restrict__ Wq, const float* __restrict__ Wk,
               const float* __restrict__ mask, const float* __restrict__ value,
               char* __restrict__ wsb){
    const int bid = blockIdx.x, tid = threadIdx.x;
    if (bid >= 1024){
        const int rb = bid - 1024;
        const int x = rb & 15, b = rb >> 4;
        const int k = tid;
        short* rt = (short*)(wsb + RT_OFF) + b*80*256;
        #pragma unroll
        for (int r = 0; r < 5; ++r){
            const int fp = x*5 + r;
            const int f = fp >> 1;
            short o = 0;
            if (f < NF){
                float m = mask[(b*NTK + k)*NF + f];
                o = (fp & 1) ? f2bf(m) : f2bf(m * value[(b*NTK + k)*NF + f]);
            }
            rt[fp*256 + k] = o;
        }
        return;
    }
    const int b = bid >> 6, side = (bid >> 5) & 1, j = (bid >> 2) & 7;
    const int t0 = (bid & 3)*64;
    const int w = tid >> 6, lane = tid & 63;
    const int col = lane & 15, quad = lane >> 4;

    __shared__ __align__(16) short sW[2*32*264];     // hi | lo, [dk][264-padded d]
    short* const sWH = sW;
    short* const sWL = sW + 32*264;

    const float* __restrict__ X = side ? key_ts : query;
    const float* __restrict__ W = (side ? Wk : Wq) + (size_t)j*ND*NDK;
    short* OH = (short*)(wsb + (side ? KPH_OFF : QPH_OFF));
    short* OL = (short*)(wsb + (side ? KPL_OFF : QPL_OFF));

    {
        const int dk0 = (tid & 7)*4, dbase = tid >> 3;
        #pragma unroll
        for (int it = 0; it < 8; ++it){
            const int d = dbase + it*32;
            f32x4 wv = *(const f32x4*)(W + (size_t)d*NDK + dk0);
            #pragma unroll
            for (int i = 0; i < 4; ++i){
                short h = f2bf(wv[i]);
                sWH[(dk0 + i)*264 + d] = h;
                sWL[(dk0 + i)*264 + d] = f2bf(wv[i] - bf2f(h));
            }
        }
    }
    __syncthreads();

    const int row = t0 + w*16 + col;
    const float* xrow = X + (size_t)(b*NTQ + row)*ND;
    f32x4 acc[2]; acc[0] = (f32x4)0.f; acc[1] = (f32x4)0.f;
    #pragma unroll
    for (int kb = 0; kb < 8; ++kb){
        const int dko = kb*32 + quad*8;
        short8 ah, al;
        cvt8(xrow + dko, ah, al);
        #pragma unroll
        for (int nt = 0; nt < 2; ++nt){
            short8 bh = *(const short8*)&sWH[(nt*16 + col)*264 + dko];
            short8 bl = *(const short8*)&sWL[(nt*16 + col)*264 + dko];
            acc[nt] = MFMA16(al, bh, acc[nt]);
            acc[nt] = MFMA16(ah, bl, acc[nt]);
            acc[nt] = MFMA16(ah, bh, acc[nt]);
        }
    }
    #pragma unroll
    for (int nt = 0; nt < 2; ++nt){
        const int dk = nt*16 + col;
        #pragma unroll
        for (int r = 0; r < 4; ++r){
            const int t = t0 + w*16 + quad*4 + r;
            float v = acc[nt][r];
            short h = f2bf(v);
            size_t o = (size_t)(((b*NH + j)*NTQ + t)*NDK + dk);
            OH[o] = h; OL[o] = f2bf(v - bf2f(h));
        }
    }
}

// ---------------- kernel 2: attention + final MLP fused ----------------
// grid (16,16): x = 16-q tile, y = b. 512 thr = 8 waves.
// phase1 (barrier-free): wave w -> j in {(w>>2)*4..+4}, keys [(w&3)*64,+64);
//   3-pass hi/lo scores (same MFMA order) -> exp -> sE[j][q][key].
// phase2: 40 (j,nt) tasks, wave w takes t = w+8i (i<5); E @ RT over kb ascending.
// epilogue: shfl-div -> latent into sHD (overlay of sE).
// phase3: final MLP (R6-verbatim arithmetic), thread (qh,d), out rows t0..t0+16.
__global__ __launch_bounds__(512, 2)
void imta_af(char* __restrict__ wsb, const float* __restrict__ value,
             const float* __restrict__ Wc, const float* __restrict__ bc,
             const float* __restrict__ Wo1, const float* __restrict__ bo1,
             const float* __restrict__ Wo2, const float* __restrict__ bo2,
             float* __restrict__ out){
    const int t0 = blockIdx.x*16, b = blockIdx.y;
    const int tid = threadIdx.x, w = tid >> 6, lane = tid & 63;
    const int col = lane & 15, quad = lane >> 4;
    __shared__ __align__(16) short sBuf[8*16*264];   // 67.6 KB: sE[8][16][264]; later sHD+sW1
    short* const sE = sBuf;
    const short* RT = (const short*)(wsb + RT_OFF) + b*80*256;

    // ---- phase 1: scores -> exp -> sE ----
    {
        const int jbase = (w >> 2)*4, keyq = (w & 3)*64;
        #pragma unroll
        for (int jo = 0; jo < 4; ++jo){
            const int j = jbase + jo;
            const short* QH = (const short*)(wsb + QPH_OFF) + (b*NH + j)*NTQ*NDK;
            const short* QL = (const short*)(wsb + QPL_OFF) + (b*NH + j)*NTQ*NDK;
            const short* KH = (const short*)(wsb + KPH_OFF) + (b*NH + j)*NTK*NDK;
            const short* KL = (const short*)(wsb + KPL_OFF) + (b*NH + j)*NTK*NDK;
            short8 ah = ld8(QH + (t0 + col)*NDK + quad*8);
            short8 al = ld8(QL + (t0 + col)*NDK + quad*8);
            #pragma unroll
            for (int nt = 0; nt < 4; ++nt){
                const int key0 = keyq + nt*16;
                short8 bh = ld8(KH + (key0 + col)*NDK + quad*8);
                short8 bl = ld8(KL + (key0 + col)*NDK + quad*8);
                f32x4 c = (f32x4)0.f;
                c = MFMA16(al, bh, c);
                c = MFMA16(ah, bl, c);
                c = MFMA16(ah, bh, c);
                const int key = key0 + col;
                #pragma unroll
                for (int r = 0; r < 4; ++r)
                    sE[j*4224 + (quad*4 + r)*264 + key] = f2bf(__expf(c[r]));
            }
        }
    }
    __syncthreads();

    // ---- phase 2: E @ RT, 5 tasks per wave ----
    f32x4 acc[5];
    int   jt[5], ntt[5];
    const short* sEp[5];
    const short* rtp[5];
    #pragma unroll
    for (int i = 0; i < 5; ++i){
        const int t = w + 8*i;
        const int j = t/5, nt = t - 5*j;
        jt[i] = j; ntt[i] = nt;
        sEp[i] = sE + j*4224 + col*264;
        rtp[i] = RT + (nt*16 + col)*256;
        acc[i] = (f32x4)0.f;
    }
    #pragma unroll
    for (int kb = 0; kb < 8; ++kb){
        const int ko = kb*32 + quad*8;
        #pragma unroll
        for (int i = 0; i < 5; ++i){
            short8 a  = *(const short8*)(sEp[i] + ko);
            short8 bb = ld8(rtp[i] + ko);
            acc[i] = MFMA16(a, bb, acc[i]);
        }
    }
    __syncthreads();                                 // all sE reads done

    // ---- epilogue: shfl-div -> sHD overlay [16][8][40]; stage sW1 ----
    float* const sHD = (float*)sBuf;
    float* const sW1 = sHD + 16*8*40;                // 216 floats
    if (tid < NF*NSF) sW1[tid] = Wo1[tid];
    #pragma unroll
    for (int i = 0; i < 5; ++i){
        const int j = jt[i], nt = ntt[i];
        #pragma unroll
        for (int r = 0; r < 4; ++r){
            float v = acc[i][r];
            float o = __shfl_xor(v, 1, 64);
            if (!(col & 1)){
                const int f = nt*8 + (col >> 1);
                if (f < NF){
                    float num = v, den = o, h;
                    if (den != 0.0f) h = num/den;
                    else {
                        float s = 0.f;
                        for (int k = 0; k < NTK; ++k) s += value[(b*NTK + k)*NF + f];
                        h = s * (1.0f/256.0f);
                    }
                    sHD[((quad*4 + r)*8 + j)*40 + f] = h;
                }
            }
        }
    }
    __syncthreads();

    // ---- phase 3: final MLP (R6-verbatim arithmetic) ----
    {
        const int d = tid & 255, qh = tid >> 8;
        float wcr[8];
        #pragma unroll
        for (int h = 0; h < 8; ++h) wcr[h] = Wc[h*ND + d];
        const float bcd = bc[d];
        float bo1r[6], wo2r[6];
        #pragma unroll
        for (int s = 0; s < 6; ++s){ bo1r[s] = bo1[s]; wo2r[s] = Wo2[s]; }
        const float bo2d = bo2[d];
        #pragma unroll
        for (int qi = 0; qi < 8; ++qi){
            const int q = qh*8 + qi;
            float a2[6];
            #pragma unroll
            for (int s = 0; s < 6; ++s) a2[s] = bo1r[s];
            #pragma unroll
            for (int f4 = 0; f4 < NF; f4 += 4){
                float4 sv[8];
                #pragma unroll
                for (int h = 0; h < 8; ++h) sv[h] = *(const float4*)&sHD[(q*8 + h)*40 + f4];
                #pragma unroll
                for (int fi = 0; fi < 4; ++fi){
                    float a = bcd;
                    #pragma unroll
                    for (int h = 0; h < 8; ++h)
                        a = fmaf(reinterpret_cast<const float*>(&sv[h])[fi], wcr[h], a);
                    float lf = fast_tanh(a);
                    const int f = f4 + fi;
                    #pragma unroll
                    for (int s = 0; s < 6; ++s)
                        a2[s] = fmaf(lf, sW1[f*NSF + s], a2[s]);
                }
            }
            float o = bo2d;
            #pragma unroll
            for (int s = 0; s < 6; ++s)
                o = fmaf(fast_tanh(a2[s]), wo2r[s], o);
            out[(b*NTQ + t0 + q)*ND + d] = o;
        }
    }
}

extern "C" void kernel_launch(void* const* d_in, const int* in_sizes, int n_in,
                              void* d_out, int out_size, void* d_ws, size_t ws_size,
                              hipStream_t stream){
    const float* query  = (const float*)d_in[0];
    const float* key_ts = (const float*)d_in[1];
    const float* value  = (const float*)d_in[2];
    const float* mask   = (const float*)d_in[3];
    const float* Wq     = (const float*)d_in[4];
    const float* Wk     = (const float*)d_in[5];
    const float* Wc     = (const float*)d_in[6];
    const float* bc     = (const float*)d_in[7];
    const float* Wo1    = (const float*)d_in[8];
    const float* bo1    = (const float*)d_in[9];
    const float* Wo2    = (const float*)d_in[10];
    const float* bo2    = (const float*)d_in[11];
    char* wsb  = (char*)d_ws;
    float* out = (float*)d_out;
    (void)in_sizes; (void)n_in; (void)out_size; (void)ws_size;

    imta_proj<<<dim3(1280),   dim3(256), 0, stream>>>(query, key_ts, Wq, Wk, mask, value, wsb);
    imta_af  <<<dim3(16, 16), dim3(512), 0, stream>>>(wsb, value, Wc, bc, Wo1, bo1, Wo2, bo2, out);
}